// Round 14
// baseline (508.554 us; speedup 1.0000x reference)
//
#include <hip/hip_runtime.h>
#include <hip/hip_bf16.h>
#include <math.h>

#define GRAPHS 128
#define SCAN_B 256
#define BM 128
#define BN 128
#define PCH 128   // nodes per pooling block
#define WSCALE 2097152.0f   // 2^21 fixed-point weight scale

typedef __attribute__((ext_vector_type(4))) int i32x4;

__device__ inline unsigned short f2b(float f) {
    unsigned int u = __float_as_uint(f);
    unsigned int r = (u + 0x7fffu + ((u >> 16) & 1u)) >> 16;  // RNE
    return (unsigned short)r;
}
__device__ inline float b2f(unsigned short u) {
    return __uint_as_float(((unsigned int)u) << 16);
}
__device__ inline void unpack8(float* v, uint4 u) {
    v[0] = b2f(u.x & 0xffffu); v[1] = b2f(u.x >> 16);
    v[2] = b2f(u.y & 0xffffu); v[3] = b2f(u.y >> 16);
    v[4] = b2f(u.z & 0xffffu); v[5] = b2f(u.z >> 16);
    v[6] = b2f(u.w & 0xffffu); v[7] = b2f(u.w >> 16);
}

__device__ inline void gload16(const void* g, void* l) {
    typedef unsigned int __attribute__((address_space(1))) gu32;
    typedef unsigned int __attribute__((address_space(3))) su32;
    __builtin_amdgcn_global_load_lds((const gu32*)g, (su32*)l, 16, 0, 0);
}

// bijective XCD chunk-major remap (m204)
__device__ inline int xcd_vid(int p, int nwg) {
    int q = nwg >> 3, r = nwg & 7, x = p & 7, ix = p >> 3;
    return (x < r ? x * (q + 1) : r * (q + 1) + (x - r) * q) + ix;
}

// ---------------- CSR build ----------------

__global__ void k_count(const int* __restrict__ dst, int* __restrict__ cnt, int E) {
    int i = blockIdx.x * blockDim.x + threadIdx.x;
    if (i < E) atomicAdd(&cnt[dst[i]], 1);
}

// single-dispatch exclusive scan + dinv + cursor init (one 1024-thread block)
__global__ __launch_bounds__(1024) void k_scan_all(const int* __restrict__ cnt,
                                                   int* __restrict__ rowstart,
                                                   float* __restrict__ dinv,
                                                   int* __restrict__ cursor, int n, int E) {
    __shared__ int sh[1024];
    int t = threadIdx.x;
    const int per = (n + 1023) / 1024;
    int i0 = t * per;
    int i1 = i0 + per; if (i1 > n) i1 = n;
    int s = 0;
    for (int i = i0; i < i1; ++i) s += cnt[i];
    sh[t] = s;
    __syncthreads();
    for (int off = 1; off < 1024; off <<= 1) {
        int v = (t >= off) ? sh[t - off] : 0;
        __syncthreads();
        sh[t] += v;
        __syncthreads();
    }
    int base = (t > 0) ? sh[t - 1] : 0;   // exclusive prefix
    for (int i = i0; i < i1; ++i) {
        int c = cnt[i];
        rowstart[i] = base;
        cursor[i] = 0;
        dinv[i] = rsqrtf((float)c + 1.0f);  // +1 self loop
        base += c;
    }
    if (t == 0) rowstart[n] = E;
}

// ---- fused scatter (csr with int fixed-point weight) + weight quant + x quant + bounds

__global__ void k_scatter_prep(
    const int* __restrict__ src, const int* __restrict__ dst,
    const float* __restrict__ dinv, const int* __restrict__ rowstart,
    int* __restrict__ cursor, int2* __restrict__ csr, int E, int nscat,
    const float* __restrict__ W1, const float* __restrict__ W2,
    const float* __restrict__ W3, signed char* __restrict__ T1,
    signed char* __restrict__ T2, signed char* __restrict__ T3,
    float* __restrict__ S1, float* __restrict__ S2, float* __restrict__ S3,
    const float* __restrict__ x, signed char* __restrict__ qx, float* __restrict__ sx,
    const float* __restrict__ g1, const float* __restrict__ be1,
    const float* __restrict__ g2, const float* __restrict__ be2,
    float* __restrict__ scf, float* __restrict__ scfi,
    int n, int mpad, int nblk) {
    int lane = threadIdx.x & 63;
    int b = (int)blockIdx.x;
    if (b < nscat) {   // edge scatter, weight pre-quantized to i24 fixed point
        int e = b * 256 + threadIdx.x;
        if (e < E) {
            int s = src[e], d = dst[e];
            int pos = rowstart[d] + atomicAdd(&cursor[d], 1);
            int2 c;
            c.x = s;
            c.y = __float2int_rn(dinv[s] * dinv[d] * WSCALE);
            csr[pos] = c;
        }
        return;
    }
    b -= nscat;
    if (b < 320) {   // weight quant: one wave per output column
        int w = b * 4 + (threadIdx.x >> 6);
        const float* W; signed char* T; float* S; int K, N, col;
        if (w < 256) { W = W1; T = T1; S = S1; K = 128; N = 256; col = w; }
        else if (w < 768) { W = W2; T = T2; S = S2; K = 256; N = 512; col = w - 256; }
        else { W = W3; T = T3; S = S3; K = 512; N = 512; col = w - 768; }
        int epl = K >> 6;
        float v[8];
        float mx = 0.f;
        for (int j = 0; j < epl; ++j) {
            float xx = W[(size_t)(lane * epl + j) * N + col];
            v[j] = xx;
            mx = fmaxf(mx, fabsf(xx));
        }
#pragma unroll
        for (int m = 1; m < 64; m <<= 1) mx = fmaxf(mx, __shfl_xor(mx, m));
        float inv = (mx > 0.f) ? 127.0f / mx : 0.f;
        signed char* tp = T + (size_t)col * K + lane * epl;
        for (int j = 0; j < epl; ++j) tp[j] = (signed char)__float2int_rn(v[j] * inv);
        if (lane == 0) S[col] = mx * (1.0f / 127.0f);
        return;
    }
    b -= 320;
    if (b == nblk - nscat - 321) {   // last block: fixed LN-quant scales
        int w = threadIdx.x >> 6;
        if (w < 2) {
            const float* g = w ? g2 : g1;
            const float* be = w ? be2 : be1;
            int nn = w ? 512 : 256;
            float mg = 0.f, mb = 0.f;
            for (int i = lane; i < nn; i += 64) {
                mg = fmaxf(mg, fabsf(g[i]));
                mb = fmaxf(mb, fabsf(be[i]));
            }
#pragma unroll
            for (int m = 1; m < 64; m <<= 1) {
                mg = fmaxf(mg, __shfl_xor(mg, m));
                mb = fmaxf(mb, __shfl_xor(mb, m));
            }
            if (lane == 0) {
                float s = (6.0f * mg + mb) * (1.0f / 127.0f);
                scf[w] = s;
                scfi[w] = 1.0f / s;
            }
        }
        return;
    }
    // x quant: one wave per row
    int row = b * 4 + (threadIdx.x >> 6);
    if (row >= mpad) return;
    signed char* qp = qx + (size_t)row * 128 + lane * 2;
    if (row >= n) {
        *(unsigned short*)qp = 0;
        if (lane == 0) sx[row] = 0.f;
        return;
    }
    float2 v = *(const float2*)(x + (size_t)row * 128 + lane * 2);
    float mx = fmaxf(fabsf(v.x), fabsf(v.y));
#pragma unroll
    for (int m = 1; m < 64; m <<= 1) mx = fmaxf(mx, __shfl_xor(mx, m));
    float inv = (mx > 0.f) ? 127.0f / mx : 0.f;
    int q0 = __float2int_rn(v.x * inv), q1 = __float2int_rn(v.y * inv);
    *(unsigned short*)qp = (unsigned short)((q0 & 0xff) | ((q1 & 0xff) << 8));
    if (lane == 0) sx[row] = mx * (1.0f / 127.0f);
}

// ------- int8 aggregation, i24 fixed-point accumulate -> int8 out + per-row scale -----
// FIXS (layers 2-3): csr.y IS the int weight (w*2^21); per-layer scale scf[li] folds
// into the output scale sa — inner loop is pure {load, load, 16x mad24}.
// Layer 1: per-row x scales -> reconstruct weight from int and scale per edge.

__device__ inline void accw(int* a, unsigned int u, int wq) {
    a[0] += __mul24((int)(signed char)(u), wq);
    a[1] += __mul24((int)(signed char)(u >> 8), wq);
    a[2] += __mul24((int)(signed char)(u >> 16), wq);
    a[3] += __mul24((int)(signed char)(u >> 24), wq);
}
__device__ inline void acc16(int* a, uint4 u, int wq) {
    accw(a, u.x, wq);
    accw(a + 4, u.y, wq);
    accw(a + 8, u.z, wq);
    accw(a + 12, u.w, wq);
}

template <int F, bool FIXS>
__global__ void k_agg8(const signed char* __restrict__ q8, const float* __restrict__ scale,
                       const float* __restrict__ scf, int li,
                       signed char* __restrict__ qa, float* __restrict__ sa,
                       const int* __restrict__ rowstart, const int2* __restrict__ csr,
                       const float* __restrict__ dinv, int n, int mpad) {
    constexpr int TPN = F / 16;       // threads per node, 16 int8 (16B) each
    constexpr int NPB = 256 / TPN;
    int node = blockIdx.x * NPB + (int)(threadIdx.x / TPN);
    int sub = (int)(threadIdx.x % TPN);
    int fo = sub * 16;
    if (node >= mpad) return;
    signed char* outp = qa + (size_t)node * F + fo;
    if (node >= n) {
        uint4 z = {0u, 0u, 0u, 0u};
        *(uint4*)outp = z;
        if (sub == 0) sa[node] = 0.f;
        return;
    }

    const signed char* qf = q8 + fo;
    float di = dinv[node];
    int a[16] = {};
    {
        uint4 u = *(const uint4*)(qf + (size_t)node * F);
        float ws = FIXS ? di * di * WSCALE : di * di * scale[node] * WSCALE;
        acc16(a, u, __float2int_rn(ws));   // self loop
    }
    int b = rowstart[node], e = rowstart[node + 1];
    int j = b;
    for (; j + 2 <= e; j += 2) {
        int2 c0 = csr[j], c1 = csr[j + 1];
        uint4 u0 = *(const uint4*)(qf + (size_t)c0.x * F);
        uint4 u1 = *(const uint4*)(qf + (size_t)c1.x * F);
        int w0, w1;
        if (FIXS) {
            w0 = c0.y;
            w1 = c1.y;
        } else {
            w0 = __float2int_rn((float)c0.y * scale[c0.x]);
            w1 = __float2int_rn((float)c1.y * scale[c1.x]);
        }
        acc16(a, u0, w0);
        acc16(a, u1, w1);
    }
    for (; j < e; ++j) {
        int2 c = csr[j];
        uint4 u = *(const uint4*)(qf + (size_t)c.x * F);
        int wq = FIXS ? c.y : __float2int_rn((float)c.y * scale[c.x]);
        acc16(a, u, wq);
    }
    // per-node max (integer), across the TPN lanes of this node group
    int amax = 0;
#pragma unroll
    for (int k = 0; k < 16; ++k) amax = max(amax, abs(a[k]));
#pragma unroll
    for (int m = 1; m < TPN; m <<= 1) amax = max(amax, __shfl_xor(amax, m));

    float inv = (amax > 0) ? 127.0f / (float)amax : 0.f;
    unsigned int ob[4];
#pragma unroll
    for (int wi = 0; wi < 4; ++wi) {
        unsigned int o = 0;
#pragma unroll
        for (int k = 0; k < 4; ++k)
            o |= ((unsigned)(__float2int_rn((float)a[wi * 4 + k] * inv) & 0xff)) << (8 * k);
        ob[wi] = o;
    }
    *(uint4*)outp = *(uint4*)ob;
    if (sub == 0) {
        float s = (float)amax * (1.0f / (127.0f * WSCALE));
        if (FIXS) s *= scf[li];   // fold per-layer source-quant scale into output scale
        sa[node] = s;
    }
}

// ------- int8 MFMA GEMM: Z = dequant(Aq @ Bq^T) + bias -> bf16, XCD-chunked -----------

__global__ __launch_bounds__(256) void k_gemm_i8(
    const signed char* __restrict__ A, const float* __restrict__ srow,
    const signed char* __restrict__ BT, const float* __restrict__ scol,
    const float* __restrict__ bias, unsigned short* __restrict__ C,
    int K, int N, int ncb) {
    __shared__ __align__(16) char sA[BM * 128];
    __shared__ __align__(16) char sB[BN * 128];

    const int vid = xcd_vid((int)blockIdx.x, (int)gridDim.x);
    const int rb = vid / ncb;
    const int cb = vid - rb * ncb;
    const int tid = threadIdx.x;
    const int lane = tid & 63;
    const int wave = tid >> 6;
    const int wr = wave >> 1, wc = wave & 1;
    const size_t row0 = (size_t)rb * BM;
    const size_t col0 = (size_t)cb * BN;

    const signed char* srcA[4];
    const signed char* srcB[4];
    char* dstA[4];
    char* dstB[4];
#pragma unroll
    for (int c = 0; c < 4; ++c) {
        int idx = c * 256 + tid;
        int row = idx >> 3;
        int cbl = ((idx & 7) << 4) ^ ((row & 7) << 4);
        srcA[c] = A + (row0 + row) * K + cbl;
        srcB[c] = BT + (col0 + row) * K + cbl;
        dstA[c] = sA + idx * 16;
        dstB[c] = sB + idx * 16;
    }

    const int fr = lane & 15;
    const int fg = lane >> 4;
    const int fsw = (lane & 7) << 4;
    int offA[4][2], offB[4][2];
#pragma unroll
    for (int t = 0; t < 4; ++t)
#pragma unroll
        for (int kk = 0; kk < 2; ++kk) {
            offA[t][kk] = (wr * 64 + t * 16 + fr) * 128 + ((kk * 64 + fg * 16) ^ fsw);
            offB[t][kk] = (wc * 64 + t * 16 + fr) * 128 + ((kk * 64 + fg * 16) ^ fsw);
        }

    i32x4 acc[4][4] = {};

    for (int k0 = 0; k0 < K; k0 += 128) {
#pragma unroll
        for (int c = 0; c < 4; ++c) gload16(srcA[c] + k0, dstA[c]);
#pragma unroll
        for (int c = 0; c < 4; ++c) gload16(srcB[c] + k0, dstB[c]);
        __syncthreads();
#pragma unroll
        for (int kk = 0; kk < 2; ++kk) {
            i32x4 av[4], bv[4];
#pragma unroll
            for (int t = 0; t < 4; ++t) av[t] = *(const i32x4*)(sA + offA[t][kk]);
#pragma unroll
            for (int t = 0; t < 4; ++t) bv[t] = *(const i32x4*)(sB + offB[t][kk]);
#pragma unroll
            for (int i = 0; i < 4; ++i)
#pragma unroll
                for (int j = 0; j < 4; ++j)
                    acc[i][j] = __builtin_amdgcn_mfma_i32_16x16x64_i8(av[i], bv[j],
                                                                      acc[i][j], 0, 0, 0);
        }
        __syncthreads();
    }

    float sr[4][4];
#pragma unroll
    for (int i = 0; i < 4; ++i)
#pragma unroll
        for (int q = 0; q < 4; ++q)
            sr[i][q] = srow[row0 + wr * 64 + i * 16 + fg * 4 + q];

#pragma unroll
    for (int i = 0; i < 4; ++i) {
#pragma unroll
        for (int j = 0; j < 4; ++j) {
            size_t r = row0 + wr * 64 + i * 16 + fg * 4;
            size_t cc = col0 + wc * 64 + j * 16 + fr;
            float scc = scol[cc];
            float bb = bias[cc];
#pragma unroll
            for (int q = 0; q < 4; ++q)
                C[(r + q) * N + cc] = f2b((float)acc[i][j][q] * (sr[i][q] * scc) + bb);
        }
    }
}

// ---- LN + LeakyReLU -> int8 with per-layer FIXED scale (clamped), wave per row -------

template <int F, bool LRELU>
__global__ void k_lnq(const unsigned short* __restrict__ z, signed char* __restrict__ q8,
                      const float* __restrict__ scfi, int li,
                      const float* __restrict__ g, const float* __restrict__ be, int mpad) {
    constexpr int V = F / 64;   // 4 (F=256) or 8 (F=512)
    int row = blockIdx.x * 4 + (threadIdx.x >> 6);
    int lane = threadIdx.x & 63;
    const unsigned short* p = z + (size_t)row * F + lane * V;
    float v[V];
    if constexpr (V == 8) {
        uint4 u = *(const uint4*)p;
        unpack8(v, u);
    } else {
        uint2 u = *(const uint2*)p;
        v[0] = b2f(u.x & 0xffffu); v[1] = b2f(u.x >> 16);
        v[2] = b2f(u.y & 0xffffu); v[3] = b2f(u.y >> 16);
    }
    float s = 0.f, q = 0.f;
#pragma unroll
    for (int k = 0; k < V; ++k) { s += v[k]; q += v[k] * v[k]; }
#pragma unroll
    for (int m = 1; m < 64; m <<= 1) {
        s += __shfl_xor(s, m);
        q += __shfl_xor(q, m);
    }
    float mu = s * (1.0f / F);
    float var = q * (1.0f / F) - mu * mu;
    float rs = rsqrtf(var + 1e-5f);
    float inv = scfi[li];   // fixed per-layer quant scale (uniform load)

    unsigned int ob[V / 4];
#pragma unroll
    for (int k = 0; k < V; k += 4) {
        unsigned int o = 0;
#pragma unroll
        for (int t = 0; t < 4; ++t) {
            float yy = (v[k + t] - mu) * rs * g[lane * V + k + t] + be[lane * V + k + t];
            if (LRELU) yy = fmaxf(yy, 0.f) + 0.01f * fminf(yy, 0.f);
            int qi = __float2int_rn(yy * inv);
            qi = min(127, max(-127, qi));
            o |= ((unsigned)(qi & 0xff)) << (8 * t);
        }
        ob[k / 4] = o;
    }
    signed char* qp = q8 + (size_t)row * F + lane * V;
    if constexpr (V == 8) *(uint2*)qp = *(uint2*)ob;
    else                  *(unsigned int*)qp = ob[0];
}

// ---------------- fused stats + LN + mean-pool: wave per row, atomics per boundary ----

__global__ void k_pool4(const unsigned short* __restrict__ z, const float* __restrict__ g,
                        const float* __restrict__ be, const int* __restrict__ batch,
                        float* __restrict__ pooled, int n) {
    int i0 = blockIdx.x * PCH;
    int iend = i0 + PCH; if (iend > n) iend = n;
    int w = threadIdx.x >> 6, lane = threadIdx.x & 63;
    int f0 = lane * 8;
    float gk[8], ek[8];
    {
        float4 ga = *(const float4*)(g + f0), gb = *(const float4*)(g + f0 + 4);
        float4 ea = *(const float4*)(be + f0), eb = *(const float4*)(be + f0 + 4);
        gk[0] = ga.x; gk[1] = ga.y; gk[2] = ga.z; gk[3] = ga.w;
        gk[4] = gb.x; gk[5] = gb.y; gk[6] = gb.z; gk[7] = gb.w;
        ek[0] = ea.x; ek[1] = ea.y; ek[2] = ea.z; ek[3] = ea.w;
        ek[4] = eb.x; ek[5] = eb.y; ek[6] = eb.z; ek[7] = eb.w;
    }
    float a[8] = {};
    int cur = -1;
    for (int i = i0 + w; i < iend; i += 4) {
        int gg = batch[i];
        if (gg != cur) {
            if (cur >= 0) {
                float* pp = pooled + (size_t)cur * 512 + f0;
#pragma unroll
                for (int k = 0; k < 8; ++k) atomicAdd(&pp[k], a[k]);
            }
#pragma unroll
            for (int k = 0; k < 8; ++k) a[k] = 0.f;
            cur = gg;
        }
        uint4 u = *(const uint4*)(z + (size_t)i * 512 + f0);
        float v[8]; unpack8(v, u);
        float s = 0.f, q = 0.f;
#pragma unroll
        for (int k = 0; k < 8; ++k) { s += v[k]; q += v[k] * v[k]; }
#pragma unroll
        for (int m = 1; m < 64; m <<= 1) {
            s += __shfl_xor(s, m);
            q += __shfl_xor(q, m);
        }
        float mu = s * (1.0f / 512.0f);
        float var = q * (1.0f / 512.0f) - mu * mu;
        float rs = rsqrtf(var + 1e-5f);
#pragma unroll
        for (int k = 0; k < 8; ++k) a[k] += (v[k] - mu) * rs * gk[k] + ek[k];
    }
    if (cur >= 0) {
        float* pp = pooled + (size_t)cur * 512 + f0;
#pragma unroll
        for (int k = 0; k < 8; ++k) atomicAdd(&pp[k], a[k]);
    }
}

// ---------------- final linear ----------------

__global__ void k_final(const float* __restrict__ pooled, const int* __restrict__ batch,
                        const float* __restrict__ Wf, const float* __restrict__ bf,
                        float* __restrict__ out, int n) {
    int gph = blockIdx.x;
    int o = threadIdx.x;
    int lo = 0, hi = n;
    while (lo < hi) { int mid = (lo + hi) >> 1; if (batch[mid] < gph) lo = mid + 1; else hi = mid; }
    int start = lo;
    lo = start; hi = n;
    while (lo < hi) { int mid = (lo + hi) >> 1; if (batch[mid] < gph + 1) lo = mid + 1; else hi = mid; }
    int end = lo;
    float inv = 1.0f / fmaxf((float)(end - start), 1.0f);

    __shared__ float p[512];
    for (int k = threadIdx.x; k < 512; k += 128) p[k] = pooled[(size_t)gph * 512 + k] * inv;
    __syncthreads();
    float acc = bf[o];
#pragma unroll 8
    for (int k = 0; k < 512; ++k) acc += p[k] * Wf[(size_t)k * 128 + o];
    out[(size_t)gph * 128 + o] = acc;
}

// ---------------- host ----------------

static inline size_t align_up(size_t x) { return (x + 255) & ~(size_t)255; }

extern "C" void kernel_launch(void* const* d_in, const int* in_sizes, int n_in,
                              void* d_out, int out_size, void* d_ws, size_t ws_size,
                              hipStream_t stream) {
    const float* x     = (const float*)d_in[0];
    const int*   ei    = (const int*)d_in[1];
    const int*   batch = (const int*)d_in[2];
    const float* W1 = (const float*)d_in[4],  *b1 = (const float*)d_in[5];
    const float* g1 = (const float*)d_in[6],  *be1= (const float*)d_in[7];
    const float* W2 = (const float*)d_in[8],  *b2 = (const float*)d_in[9];
    const float* g2 = (const float*)d_in[10], *be2= (const float*)d_in[11];
    const float* W3 = (const float*)d_in[12], *b3 = (const float*)d_in[13];
    const float* g3 = (const float*)d_in[14], *be3= (const float*)d_in[15];
    const float* Wf = (const float*)d_in[16], *bf = (const float*)d_in[17];
    float* out = (float*)d_out;

    const int N = in_sizes[0] / 128;   // 50000
    const int E = in_sizes[1] / 2;     // 800000
    const int Mpad = ((N + BM - 1) / BM) * BM;   // 50048
    const int* src = ei;
    const int* dst = ei + E;

    char* ws = (char*)d_ws;
    size_t off = 0;
    auto take = [&](size_t bytes) { char* p = ws + off; off += align_up(bytes); return p; };

    // cnt + pooled adjacent -> single memset
    int*            cnt     = (int*)  take((size_t)N * 4);
    float*          pooled  = (float*)take((size_t)GRAPHS * 512 * 4);
    unsigned short* zb      = (unsigned short*)take((size_t)Mpad * 512 * 2);  // GEMM out (bf16)
    signed char*    qa      = (signed char*)take((size_t)Mpad * 512);         // agg out (int8)
    float*          sa      = (float*)take((size_t)Mpad * 4);
    signed char*    q8      = (signed char*)take((size_t)Mpad * 512);         // LN out (int8)
    signed char*    q8x     = (signed char*)take((size_t)Mpad * 128);         // int8 x
    float*          sx      = (float*)take((size_t)Mpad * 4);
    signed char*    wq1     = (signed char*)take((size_t)256 * 128);
    signed char*    wq2     = (signed char*)take((size_t)512 * 256);
    signed char*    wq3     = (signed char*)take((size_t)512 * 512);
    float*          sc1     = (float*)take(256 * 4);
    float*          sc2     = (float*)take(512 * 4);
    float*          sc3     = (float*)take(512 * 4);
    float*          scf     = (float*)take(2 * 4);
    float*          scfi    = (float*)take(2 * 4);
    float*          dinv    = (float*)take((size_t)N * 4);
    int*            rowstart= (int*)  take((size_t)(N + 1) * 4);
    int*            cursor  = (int*)  take((size_t)N * 4);
    int2*           csr     = (int2*) take((size_t)E * 8);

    const int NR4 = Mpad / 4;
    const int SCAT = (E + 255) / 256;
    const int nblk = SCAT + 320 + NR4 + 1;

    // single merged memset (cnt .. pooled, adjacent allocations)
    hipMemsetAsync(cnt, 0, (size_t)((char*)(pooled + GRAPHS * 512) - (char*)cnt), stream);

    // CSR build (2 dispatches) + fused scatter/prep
    k_count<<<(E + 255) / 256, 256, 0, stream>>>(dst, cnt, E);
    k_scan_all<<<1, 1024, 0, stream>>>(cnt, rowstart, dinv, cursor, N, E);
    k_scatter_prep<<<nblk, 256, 0, stream>>>(src, dst, dinv, rowstart, cursor, csr, E, SCAT,
                                             W1, W2, W3, wq1, wq2, wq3, sc1, sc2, sc3,
                                             x, q8x, sx, g1, be1, g2, be2, scf, scfi,
                                             N, Mpad, nblk);

    // Layer 1: per-row-scale gather -> i8 GEMM(K=128,N=256) -> LN+lrelu (fixed sc0)
    k_agg8<128, false><<<Mpad / 32, 256, 0, stream>>>(q8x, sx, nullptr, 0, qa, sa,
                                                      rowstart, csr, dinv, N, Mpad);
    k_gemm_i8<<<(Mpad / BM) * 2, 256, 0, stream>>>(qa, sa, wq1, sc1, b1, zb, 128, 256, 2);
    k_lnq<256, true><<<NR4, 256, 0, stream>>>(zb, q8, scfi, 0, g1, be1, Mpad);

    // Layer 2: pure-int gather -> GEMM -> LN (fixed sc1)
    k_agg8<256, true><<<Mpad / 16, 256, 0, stream>>>(q8, nullptr, scf, 0, qa, sa,
                                                     rowstart, csr, dinv, N, Mpad);
    k_gemm_i8<<<(Mpad / BM) * 4, 256, 0, stream>>>(qa, sa, wq2, sc2, b2, zb, 256, 512, 4);
    k_lnq<512, true><<<NR4, 256, 0, stream>>>(zb, q8, scfi, 1, g2, be2, Mpad);

    // Layer 3: pure-int gather -> GEMM -> fused LN+pool
    k_agg8<512, true><<<Mpad / 8, 256, 0, stream>>>(q8, nullptr, scf, 1, qa, sa,
                                                    rowstart, csr, dinv, N, Mpad);
    k_gemm_i8<<<(Mpad / BM) * 4, 256, 0, stream>>>(qa, sa, wq3, sc3, b3, zb, 512, 512, 4);

    // pool (stats + LN fused) + final
    k_pool4<<<(N + PCH - 1) / PCH, 256, 0, stream>>>(zb, g3, be3, batch, pooled, N);
    k_final<<<GRAPHS, 128, 0, stream>>>(pooled, batch, Wf, bf, out, N);
}

// Round 15
// 381.948 us; speedup vs baseline: 1.3315x; 1.3315x over previous
//
#include <hip/hip_runtime.h>
#include <hip/hip_bf16.h>
#include <math.h>

#define GRAPHS 128
#define SCAN_B 256
#define BM 128
#define BN 128
#define PCH 128   // nodes per pooling block
#define WSCALE 2097152.0f   // 2^21 fixed-point weight scale

typedef __attribute__((ext_vector_type(4))) int i32x4;

__device__ inline unsigned short f2b(float f) {
    unsigned int u = __float_as_uint(f);
    unsigned int r = (u + 0x7fffu + ((u >> 16) & 1u)) >> 16;  // RNE
    return (unsigned short)r;
}
__device__ inline float b2f(unsigned short u) {
    return __uint_as_float(((unsigned int)u) << 16);
}
__device__ inline void unpack8(float* v, uint4 u) {
    v[0] = b2f(u.x & 0xffffu); v[1] = b2f(u.x >> 16);
    v[2] = b2f(u.y & 0xffffu); v[3] = b2f(u.y >> 16);
    v[4] = b2f(u.z & 0xffffu); v[5] = b2f(u.z >> 16);
    v[6] = b2f(u.w & 0xffffu); v[7] = b2f(u.w >> 16);
}

__device__ inline void gload16(const void* g, void* l) {
    typedef unsigned int __attribute__((address_space(1))) gu32;
    typedef unsigned int __attribute__((address_space(3))) su32;
    __builtin_amdgcn_global_load_lds((const gu32*)g, (su32*)l, 16, 0, 0);
}

// bijective XCD chunk-major remap (m204)
__device__ inline int xcd_vid(int p, int nwg) {
    int q = nwg >> 3, r = nwg & 7, x = p & 7, ix = p >> 3;
    return (x < r ? x * (q + 1) : r * (q + 1) + (x - r) * q) + ix;
}

// ---------------- CSR build (3-dispatch parallel scan, R13-proven) ----------------

__global__ void k_count(const int* __restrict__ dst, int* __restrict__ cnt, int E) {
    int i = blockIdx.x * blockDim.x + threadIdx.x;
    if (i < E) atomicAdd(&cnt[dst[i]], 1);
}

__global__ void k_scan1(const int* __restrict__ cnt, int* __restrict__ excl,
                        int* __restrict__ bsum, int n) {
    __shared__ int sh[SCAN_B];
    int t = threadIdx.x;
    int i = blockIdx.x * SCAN_B + t;
    int v = (i < n) ? cnt[i] : 0;
    sh[t] = v;
    __syncthreads();
    for (int off = 1; off < SCAN_B; off <<= 1) {
        int x = (t >= off) ? sh[t - off] : 0;
        __syncthreads();
        sh[t] += x;
        __syncthreads();
    }
    if (i < n) excl[i] = sh[t] - v;
    if (t == SCAN_B - 1) bsum[blockIdx.x] = sh[t];
}

__global__ void k_scan2(int* __restrict__ bsum, int nb) {
    __shared__ int sh[SCAN_B];
    int t = threadIdx.x;
    int v = (t < nb) ? bsum[t] : 0;
    sh[t] = v;
    __syncthreads();
    for (int off = 1; off < SCAN_B; off <<= 1) {
        int x = (t >= off) ? sh[t - off] : 0;
        __syncthreads();
        sh[t] += x;
        __syncthreads();
    }
    if (t < nb) bsum[t] = sh[t] - v;
}

__global__ void k_scan3(int* __restrict__ rowstart, const int* __restrict__ bsum,
                        const int* __restrict__ cnt, float* __restrict__ dinv,
                        int* __restrict__ cursor, int n, int E) {
    int i = blockIdx.x * SCAN_B + threadIdx.x;
    if (i < n) {
        rowstart[i] += bsum[blockIdx.x];
        cursor[i] = 0;
        dinv[i] = rsqrtf((float)cnt[i] + 1.0f);  // +1 self loop
    }
    if (i == 0) rowstart[n] = E;
}

// ---- fused scatter (csr with int fixed-point weight) + weight quant + x quant + bounds

__global__ void k_scatter_prep(
    const int* __restrict__ src, const int* __restrict__ dst,
    const float* __restrict__ dinv, const int* __restrict__ rowstart,
    int* __restrict__ cursor, int2* __restrict__ csr, int E, int nscat,
    const float* __restrict__ W1, const float* __restrict__ W2,
    const float* __restrict__ W3, signed char* __restrict__ T1,
    signed char* __restrict__ T2, signed char* __restrict__ T3,
    float* __restrict__ S1, float* __restrict__ S2, float* __restrict__ S3,
    const float* __restrict__ x, signed char* __restrict__ qx, float* __restrict__ sx,
    const float* __restrict__ g1, const float* __restrict__ be1,
    const float* __restrict__ g2, const float* __restrict__ be2,
    float* __restrict__ scf, float* __restrict__ scfi,
    int n, int mpad, int nblk) {
    int lane = threadIdx.x & 63;
    int b = (int)blockIdx.x;
    if (b < nscat) {   // edge scatter, weight pre-quantized to i24 fixed point
        int e = b * 256 + threadIdx.x;
        if (e < E) {
            int s = src[e], d = dst[e];
            int pos = rowstart[d] + atomicAdd(&cursor[d], 1);
            int2 c;
            c.x = s;
            c.y = __float2int_rn(dinv[s] * dinv[d] * WSCALE);
            csr[pos] = c;
        }
        return;
    }
    b -= nscat;
    if (b < 320) {   // weight quant: one wave per output column
        int w = b * 4 + (threadIdx.x >> 6);
        const float* W; signed char* T; float* S; int K, N, col;
        if (w < 256) { W = W1; T = T1; S = S1; K = 128; N = 256; col = w; }
        else if (w < 768) { W = W2; T = T2; S = S2; K = 256; N = 512; col = w - 256; }
        else { W = W3; T = T3; S = S3; K = 512; N = 512; col = w - 768; }
        int epl = K >> 6;
        float v[8];
        float mx = 0.f;
        for (int j = 0; j < epl; ++j) {
            float xx = W[(size_t)(lane * epl + j) * N + col];
            v[j] = xx;
            mx = fmaxf(mx, fabsf(xx));
        }
#pragma unroll
        for (int m = 1; m < 64; m <<= 1) mx = fmaxf(mx, __shfl_xor(mx, m));
        float inv = (mx > 0.f) ? 127.0f / mx : 0.f;
        signed char* tp = T + (size_t)col * K + lane * epl;
        for (int j = 0; j < epl; ++j) tp[j] = (signed char)__float2int_rn(v[j] * inv);
        if (lane == 0) S[col] = mx * (1.0f / 127.0f);
        return;
    }
    b -= 320;
    if (b == nblk - nscat - 321) {   // last block: fixed LN-quant scales
        int w = threadIdx.x >> 6;
        if (w < 2) {
            const float* g = w ? g2 : g1;
            const float* be = w ? be2 : be1;
            int nn = w ? 512 : 256;
            float mg = 0.f, mb = 0.f;
            for (int i = lane; i < nn; i += 64) {
                mg = fmaxf(mg, fabsf(g[i]));
                mb = fmaxf(mb, fabsf(be[i]));
            }
#pragma unroll
            for (int m = 1; m < 64; m <<= 1) {
                mg = fmaxf(mg, __shfl_xor(mg, m));
                mb = fmaxf(mb, __shfl_xor(mb, m));
            }
            if (lane == 0) {
                float s = (6.0f * mg + mb) * (1.0f / 127.0f);
                scf[w] = s;
                scfi[w] = 1.0f / s;
            }
        }
        return;
    }
    // x quant: one wave per row
    int row = b * 4 + (threadIdx.x >> 6);
    if (row >= mpad) return;
    signed char* qp = qx + (size_t)row * 128 + lane * 2;
    if (row >= n) {
        *(unsigned short*)qp = 0;
        if (lane == 0) sx[row] = 0.f;
        return;
    }
    float2 v = *(const float2*)(x + (size_t)row * 128 + lane * 2);
    float mx = fmaxf(fabsf(v.x), fabsf(v.y));
#pragma unroll
    for (int m = 1; m < 64; m <<= 1) mx = fmaxf(mx, __shfl_xor(mx, m));
    float inv = (mx > 0.f) ? 127.0f / mx : 0.f;
    int q0 = __float2int_rn(v.x * inv), q1 = __float2int_rn(v.y * inv);
    *(unsigned short*)qp = (unsigned short)((q0 & 0xff) | ((q1 & 0xff) << 8));
    if (lane == 0) sx[row] = mx * (1.0f / 127.0f);
}

// ------- int8 aggregation, i24 fixed-point accumulate -> int8 out + per-row scale -----

__device__ inline void accw(int* a, unsigned int u, int wq) {
    a[0] += __mul24((int)(signed char)(u), wq);
    a[1] += __mul24((int)(signed char)(u >> 8), wq);
    a[2] += __mul24((int)(signed char)(u >> 16), wq);
    a[3] += __mul24((int)(signed char)(u >> 24), wq);
}
__device__ inline void acc16(int* a, uint4 u, int wq) {
    accw(a, u.x, wq);
    accw(a + 4, u.y, wq);
    accw(a + 8, u.z, wq);
    accw(a + 12, u.w, wq);
}

template <int F, bool FIXS>
__global__ void k_agg8(const signed char* __restrict__ q8, const float* __restrict__ scale,
                       const float* __restrict__ scf, int li,
                       signed char* __restrict__ qa, float* __restrict__ sa,
                       const int* __restrict__ rowstart, const int2* __restrict__ csr,
                       const float* __restrict__ dinv, int n, int mpad) {
    constexpr int TPN = F / 16;       // threads per node, 16 int8 (16B) each
    constexpr int NPB = 256 / TPN;
    int node = blockIdx.x * NPB + (int)(threadIdx.x / TPN);
    int sub = (int)(threadIdx.x % TPN);
    int fo = sub * 16;
    if (node >= mpad) return;
    signed char* outp = qa + (size_t)node * F + fo;
    if (node >= n) {
        uint4 z = {0u, 0u, 0u, 0u};
        *(uint4*)outp = z;
        if (sub == 0) sa[node] = 0.f;
        return;
    }

    const signed char* qf = q8 + fo;
    float di = dinv[node];
    int a[16] = {};
    {
        uint4 u = *(const uint4*)(qf + (size_t)node * F);
        float ws = FIXS ? di * di * WSCALE : di * di * scale[node] * WSCALE;
        acc16(a, u, __float2int_rn(ws));   // self loop
    }
    int b = rowstart[node], e = rowstart[node + 1];
    int j = b;
    for (; j + 2 <= e; j += 2) {
        int2 c0 = csr[j], c1 = csr[j + 1];
        uint4 u0 = *(const uint4*)(qf + (size_t)c0.x * F);
        uint4 u1 = *(const uint4*)(qf + (size_t)c1.x * F);
        int w0, w1;
        if (FIXS) {
            w0 = c0.y;
            w1 = c1.y;
        } else {
            w0 = __float2int_rn((float)c0.y * scale[c0.x]);
            w1 = __float2int_rn((float)c1.y * scale[c1.x]);
        }
        acc16(a, u0, w0);
        acc16(a, u1, w1);
    }
    for (; j < e; ++j) {
        int2 c = csr[j];
        uint4 u = *(const uint4*)(qf + (size_t)c.x * F);
        int wq = FIXS ? c.y : __float2int_rn((float)c.y * scale[c.x]);
        acc16(a, u, wq);
    }
    // per-node max (integer), across the TPN lanes of this node group
    int amax = 0;
#pragma unroll
    for (int k = 0; k < 16; ++k) amax = max(amax, abs(a[k]));
#pragma unroll
    for (int m = 1; m < TPN; m <<= 1) amax = max(amax, __shfl_xor(amax, m));

    float inv = (amax > 0) ? 127.0f / (float)amax : 0.f;
    unsigned int ob[4];
#pragma unroll
    for (int wi = 0; wi < 4; ++wi) {
        unsigned int o = 0;
#pragma unroll
        for (int k = 0; k < 4; ++k)
            o |= ((unsigned)(__float2int_rn((float)a[wi * 4 + k] * inv) & 0xff)) << (8 * k);
        ob[wi] = o;
    }
    *(uint4*)outp = *(uint4*)ob;
    if (sub == 0) {
        float s = (float)amax * (1.0f / (127.0f * WSCALE));
        if (FIXS) s *= scf[li];   // fold per-layer source-quant scale into output scale
        sa[node] = s;
    }
}

// ------- int8 MFMA GEMM: Z = dequant(Aq @ Bq^T) + bias -> bf16, XCD-chunked -----------

__global__ __launch_bounds__(256) void k_gemm_i8(
    const signed char* __restrict__ A, const float* __restrict__ srow,
    const signed char* __restrict__ BT, const float* __restrict__ scol,
    const float* __restrict__ bias, unsigned short* __restrict__ C,
    int K, int N, int ncb) {
    __shared__ __align__(16) char sA[BM * 128];
    __shared__ __align__(16) char sB[BN * 128];

    const int vid = xcd_vid((int)blockIdx.x, (int)gridDim.x);
    const int rb = vid / ncb;
    const int cb = vid - rb * ncb;
    const int tid = threadIdx.x;
    const int lane = tid & 63;
    const int wave = tid >> 6;
    const int wr = wave >> 1, wc = wave & 1;
    const size_t row0 = (size_t)rb * BM;
    const size_t col0 = (size_t)cb * BN;

    const signed char* srcA[4];
    const signed char* srcB[4];
    char* dstA[4];
    char* dstB[4];
#pragma unroll
    for (int c = 0; c < 4; ++c) {
        int idx = c * 256 + tid;
        int row = idx >> 3;
        int cbl = ((idx & 7) << 4) ^ ((row & 7) << 4);
        srcA[c] = A + (row0 + row) * K + cbl;
        srcB[c] = BT + (col0 + row) * K + cbl;
        dstA[c] = sA + idx * 16;
        dstB[c] = sB + idx * 16;
    }

    const int fr = lane & 15;
    const int fg = lane >> 4;
    const int fsw = (lane & 7) << 4;
    int offA[4][2], offB[4][2];
#pragma unroll
    for (int t = 0; t < 4; ++t)
#pragma unroll
        for (int kk = 0; kk < 2; ++kk) {
            offA[t][kk] = (wr * 64 + t * 16 + fr) * 128 + ((kk * 64 + fg * 16) ^ fsw);
            offB[t][kk] = (wc * 64 + t * 16 + fr) * 128 + ((kk * 64 + fg * 16) ^ fsw);
        }

    i32x4 acc[4][4] = {};

    for (int k0 = 0; k0 < K; k0 += 128) {
#pragma unroll
        for (int c = 0; c < 4; ++c) gload16(srcA[c] + k0, dstA[c]);
#pragma unroll
        for (int c = 0; c < 4; ++c) gload16(srcB[c] + k0, dstB[c]);
        __syncthreads();
#pragma unroll
        for (int kk = 0; kk < 2; ++kk) {
            i32x4 av[4], bv[4];
#pragma unroll
            for (int t = 0; t < 4; ++t) av[t] = *(const i32x4*)(sA + offA[t][kk]);
#pragma unroll
            for (int t = 0; t < 4; ++t) bv[t] = *(const i32x4*)(sB + offB[t][kk]);
#pragma unroll
            for (int i = 0; i < 4; ++i)
#pragma unroll
                for (int j = 0; j < 4; ++j)
                    acc[i][j] = __builtin_amdgcn_mfma_i32_16x16x64_i8(av[i], bv[j],
                                                                      acc[i][j], 0, 0, 0);
        }
        __syncthreads();
    }

    float sr[4][4];
#pragma unroll
    for (int i = 0; i < 4; ++i)
#pragma unroll
        for (int q = 0; q < 4; ++q)
            sr[i][q] = srow[row0 + wr * 64 + i * 16 + fg * 4 + q];

#pragma unroll
    for (int i = 0; i < 4; ++i) {
#pragma unroll
        for (int j = 0; j < 4; ++j) {
            size_t r = row0 + wr * 64 + i * 16 + fg * 4;
            size_t cc = col0 + wc * 64 + j * 16 + fr;
            float scc = scol[cc];
            float bb = bias[cc];
#pragma unroll
            for (int q = 0; q < 4; ++q)
                C[(r + q) * N + cc] = f2b((float)acc[i][j][q] * (sr[i][q] * scc) + bb);
        }
    }
}

// ---- LN + LeakyReLU -> int8 with per-layer FIXED scale (clamped), wave per row -------

template <int F, bool LRELU>
__global__ void k_lnq(const unsigned short* __restrict__ z, signed char* __restrict__ q8,
                      const float* __restrict__ scfi, int li,
                      const float* __restrict__ g, const float* __restrict__ be, int mpad) {
    constexpr int V = F / 64;   // 4 (F=256) or 8 (F=512)
    int row = blockIdx.x * 4 + (threadIdx.x >> 6);
    int lane = threadIdx.x & 63;
    const unsigned short* p = z + (size_t)row * F + lane * V;
    float v[V];
    if constexpr (V == 8) {
        uint4 u = *(const uint4*)p;
        unpack8(v, u);
    } else {
        uint2 u = *(const uint2*)p;
        v[0] = b2f(u.x & 0xffffu); v[1] = b2f(u.x >> 16);
        v[2] = b2f(u.y & 0xffffu); v[3] = b2f(u.y >> 16);
    }
    float s = 0.f, q = 0.f;
#pragma unroll
    for (int k = 0; k < V; ++k) { s += v[k]; q += v[k] * v[k]; }
#pragma unroll
    for (int m = 1; m < 64; m <<= 1) {
        s += __shfl_xor(s, m);
        q += __shfl_xor(q, m);
    }
    float mu = s * (1.0f / F);
    float var = q * (1.0f / F) - mu * mu;
    float rs = rsqrtf(var + 1e-5f);
    float inv = scfi[li];   // fixed per-layer quant scale (uniform load)

    unsigned int ob[V / 4];
#pragma unroll
    for (int k = 0; k < V; k += 4) {
        unsigned int o = 0;
#pragma unroll
        for (int t = 0; t < 4; ++t) {
            float yy = (v[k + t] - mu) * rs * g[lane * V + k + t] + be[lane * V + k + t];
            if (LRELU) yy = fmaxf(yy, 0.f) + 0.01f * fminf(yy, 0.f);
            int qi = __float2int_rn(yy * inv);
            qi = min(127, max(-127, qi));
            o |= ((unsigned)(qi & 0xff)) << (8 * t);
        }
        ob[k / 4] = o;
    }
    signed char* qp = q8 + (size_t)row * F + lane * V;
    if constexpr (V == 8) *(uint2*)qp = *(uint2*)ob;
    else                  *(unsigned int*)qp = ob[0];
}

// ---------------- fused stats + LN + mean-pool: wave per row, atomics per boundary ----

__global__ void k_pool4(const unsigned short* __restrict__ z, const float* __restrict__ g,
                        const float* __restrict__ be, const int* __restrict__ batch,
                        float* __restrict__ pooled, int n) {
    int i0 = blockIdx.x * PCH;
    int iend = i0 + PCH; if (iend > n) iend = n;
    int w = threadIdx.x >> 6, lane = threadIdx.x & 63;
    int f0 = lane * 8;
    float gk[8], ek[8];
    {
        float4 ga = *(const float4*)(g + f0), gb = *(const float4*)(g + f0 + 4);
        float4 ea = *(const float4*)(be + f0), eb = *(const float4*)(be + f0 + 4);
        gk[0] = ga.x; gk[1] = ga.y; gk[2] = ga.z; gk[3] = ga.w;
        gk[4] = gb.x; gk[5] = gb.y; gk[6] = gb.z; gk[7] = gb.w;
        ek[0] = ea.x; ek[1] = ea.y; ek[2] = ea.z; ek[3] = ea.w;
        ek[4] = eb.x; ek[5] = eb.y; ek[6] = eb.z; ek[7] = eb.w;
    }
    float a[8] = {};
    int cur = -1;
    for (int i = i0 + w; i < iend; i += 4) {
        int gg = batch[i];
        if (gg != cur) {
            if (cur >= 0) {
                float* pp = pooled + (size_t)cur * 512 + f0;
#pragma unroll
                for (int k = 0; k < 8; ++k) atomicAdd(&pp[k], a[k]);
            }
#pragma unroll
            for (int k = 0; k < 8; ++k) a[k] = 0.f;
            cur = gg;
        }
        uint4 u = *(const uint4*)(z + (size_t)i * 512 + f0);
        float v[8]; unpack8(v, u);
        float s = 0.f, q = 0.f;
#pragma unroll
        for (int k = 0; k < 8; ++k) { s += v[k]; q += v[k] * v[k]; }
#pragma unroll
        for (int m = 1; m < 64; m <<= 1) {
            s += __shfl_xor(s, m);
            q += __shfl_xor(q, m);
        }
        float mu = s * (1.0f / 512.0f);
        float var = q * (1.0f / 512.0f) - mu * mu;
        float rs = rsqrtf(var + 1e-5f);
#pragma unroll
        for (int k = 0; k < 8; ++k) a[k] += (v[k] - mu) * rs * gk[k] + ek[k];
    }
    if (cur >= 0) {
        float* pp = pooled + (size_t)cur * 512 + f0;
#pragma unroll
        for (int k = 0; k < 8; ++k) atomicAdd(&pp[k], a[k]);
    }
}

// ---------------- final linear ----------------

__global__ void k_final(const float* __restrict__ pooled, const int* __restrict__ batch,
                        const float* __restrict__ Wf, const float* __restrict__ bf,
                        float* __restrict__ out, int n) {
    int gph = blockIdx.x;
    int o = threadIdx.x;
    int lo = 0, hi = n;
    while (lo < hi) { int mid = (lo + hi) >> 1; if (batch[mid] < gph) lo = mid + 1; else hi = mid; }
    int start = lo;
    lo = start; hi = n;
    while (lo < hi) { int mid = (lo + hi) >> 1; if (batch[mid] < gph + 1) lo = mid + 1; else hi = mid; }
    int end = lo;
    float inv = 1.0f / fmaxf((float)(end - start), 1.0f);

    __shared__ float p[512];
    for (int k = threadIdx.x; k < 512; k += 128) p[k] = pooled[(size_t)gph * 512 + k] * inv;
    __syncthreads();
    float acc = bf[o];
#pragma unroll 8
    for (int k = 0; k < 512; ++k) acc += p[k] * Wf[(size_t)k * 128 + o];
    out[(size_t)gph * 128 + o] = acc;
}

// ---------------- host ----------------

static inline size_t align_up(size_t x) { return (x + 255) & ~(size_t)255; }

extern "C" void kernel_launch(void* const* d_in, const int* in_sizes, int n_in,
                              void* d_out, int out_size, void* d_ws, size_t ws_size,
                              hipStream_t stream) {
    const float* x     = (const float*)d_in[0];
    const int*   ei    = (const int*)d_in[1];
    const int*   batch = (const int*)d_in[2];
    const float* W1 = (const float*)d_in[4],  *b1 = (const float*)d_in[5];
    const float* g1 = (const float*)d_in[6],  *be1= (const float*)d_in[7];
    const float* W2 = (const float*)d_in[8],  *b2 = (const float*)d_in[9];
    const float* g2 = (const float*)d_in[10], *be2= (const float*)d_in[11];
    const float* W3 = (const float*)d_in[12], *b3 = (const float*)d_in[13];
    const float* g3 = (const float*)d_in[14], *be3= (const float*)d_in[15];
    const float* Wf = (const float*)d_in[16], *bf = (const float*)d_in[17];
    float* out = (float*)d_out;

    const int N = in_sizes[0] / 128;   // 50000
    const int E = in_sizes[1] / 2;     // 800000
    const int Mpad = ((N + BM - 1) / BM) * BM;   // 50048
    const int* src = ei;
    const int* dst = ei + E;

    char* ws = (char*)d_ws;
    size_t off = 0;
    auto take = [&](size_t bytes) { char* p = ws + off; off += align_up(bytes); return p; };

    // cnt + pooled adjacent -> single memset
    int*            cnt     = (int*)  take((size_t)N * 4);
    float*          pooled  = (float*)take((size_t)GRAPHS * 512 * 4);
    unsigned short* zb      = (unsigned short*)take((size_t)Mpad * 512 * 2);  // GEMM out (bf16)
    signed char*    qa      = (signed char*)take((size_t)Mpad * 512);         // agg out (int8)
    float*          sa      = (float*)take((size_t)Mpad * 4);
    signed char*    q8      = (signed char*)take((size_t)Mpad * 512);         // LN out (int8)
    signed char*    q8x     = (signed char*)take((size_t)Mpad * 128);         // int8 x
    float*          sx      = (float*)take((size_t)Mpad * 4);
    signed char*    wq1     = (signed char*)take((size_t)256 * 128);
    signed char*    wq2     = (signed char*)take((size_t)512 * 256);
    signed char*    wq3     = (signed char*)take((size_t)512 * 512);
    float*          sc1     = (float*)take(256 * 4);
    float*          sc2     = (float*)take(512 * 4);
    float*          sc3     = (float*)take(512 * 4);
    float*          scf     = (float*)take(2 * 4);
    float*          scfi    = (float*)take(2 * 4);
    float*          dinv    = (float*)take((size_t)N * 4);
    int*            rowstart= (int*)  take((size_t)(N + 1) * 4);
    int*            cursor  = (int*)  take((size_t)N * 4);
    int*            bsum    = (int*)  take((size_t)SCAN_B * 4);
    int2*           csr     = (int2*) take((size_t)E * 8);

    const int nb = (N + SCAN_B - 1) / SCAN_B;
    const int NR4 = Mpad / 4;
    const int SCAT = (E + 255) / 256;
    const int nblk = SCAT + 320 + NR4 + 1;

    // single merged memset (cnt .. pooled, adjacent allocations)
    hipMemsetAsync(cnt, 0, (size_t)((char*)(pooled + GRAPHS * 512) - (char*)cnt), stream);

    // CSR build (parallel 3-dispatch scan) + fused scatter/prep
    k_count<<<(E + 255) / 256, 256, 0, stream>>>(dst, cnt, E);
    k_scan1<<<nb, SCAN_B, 0, stream>>>(cnt, rowstart, bsum, N);
    k_scan2<<<1, SCAN_B, 0, stream>>>(bsum, nb);
    k_scan3<<<nb, SCAN_B, 0, stream>>>(rowstart, bsum, cnt, dinv, cursor, N, E);
    k_scatter_prep<<<nblk, 256, 0, stream>>>(src, dst, dinv, rowstart, cursor, csr, E, SCAT,
                                             W1, W2, W3, wq1, wq2, wq3, sc1, sc2, sc3,
                                             x, q8x, sx, g1, be1, g2, be2, scf, scfi,
                                             N, Mpad, nblk);

    // Layer 1: per-row-scale gather -> i8 GEMM(K=128,N=256) -> LN+lrelu (fixed sc0)
    k_agg8<128, false><<<Mpad / 32, 256, 0, stream>>>(q8x, sx, nullptr, 0, qa, sa,
                                                      rowstart, csr, dinv, N, Mpad);
    k_gemm_i8<<<(Mpad / BM) * 2, 256, 0, stream>>>(qa, sa, wq1, sc1, b1, zb, 128, 256, 2);
    k_lnq<256, true><<<NR4, 256, 0, stream>>>(zb, q8, scfi, 0, g1, be1, Mpad);

    // Layer 2: pure-int gather -> GEMM -> LN (fixed sc1)
    k_agg8<256, true><<<Mpad / 16, 256, 0, stream>>>(q8, nullptr, scf, 0, qa, sa,
                                                     rowstart, csr, dinv, N, Mpad);
    k_gemm_i8<<<(Mpad / BM) * 4, 256, 0, stream>>>(qa, sa, wq2, sc2, b2, zb, 256, 512, 4);
    k_lnq<512, true><<<NR4, 256, 0, stream>>>(zb, q8, scfi, 1, g2, be2, Mpad);

    // Layer 3: pure-int gather -> GEMM -> fused LN+pool
    k_agg8<512, true><<<Mpad / 8, 256, 0, stream>>>(q8, nullptr, scf, 1, qa, sa,
                                                    rowstart, csr, dinv, N, Mpad);
    k_gemm_i8<<<(Mpad / BM) * 4, 256, 0, stream>>>(qa, sa, wq3, sc3, b3, zb, 512, 512, 4);

    // pool (stats + LN fused) + final
    k_pool4<<<(N + PCH - 1) / PCH, 256, 0, stream>>>(zb, g3, be3, batch, pooled, N);
    k_final<<<GRAPHS, 128, 0, stream>>>(pooled, batch, Wf, bf, out, N);
}